// Round 8
// baseline (10829.610 us; speedup 1.0000x reference)
//
#include <hip/hip_runtime.h>

#define WGSZ 1024
#define NWG  64

namespace {
constexpr int kN = 2048, kH = 256, kGW = 512;
// Transposed-weight workspace offsets (floats); layout [k4][row] float4s.
constexpr size_t OFF_ELA2 = 0;          // 4x256x256   -> Rg=1024 K4=64
constexpr size_t OFF_ELM1 = 262144;     // 4x256x4096  -> Rg=1024 K4=1024
constexpr size_t OFF_ELM2 = 4456448;    // 4x256x256
constexpr size_t OFF_EBL1 = 4718592;    // 4x256x512   -> Rg=1024 K4=128
constexpr size_t OFF_EBL2 = 5242880;
constexpr size_t OFF_DM1  = 5505024;
constexpr size_t OFF_DV1  = 5767168;
constexpr size_t OFF_WIH  = 6029312;    // 4x2x1024x256 -> Rg=8192 K4=64
constexpr size_t OFF_WHH  = 8126464;
constexpr size_t WS_FLOATS = 10223616;  // ~39 MB
}

// np.argmin(|centers - v|), first index on tie.
__device__ __forceinline__ int bin_idx(float v) {
  float t = fmaf(v, 5.0f, 63.5f);
  int i0 = (int)floorf(t);
  int c0 = i0 - 1; c0 = c0 < 0 ? 0 : (c0 > 127 ? 127 : c0);
  int c1 = i0;     c1 = c1 < 0 ? 0 : (c1 > 127 ? 127 : c1);
  int c2 = i0 + 1; c2 = c2 < 0 ? 0 : (c2 > 127 ? 127 : c2);
  float d0 = fabsf(__fmul_rn(__fadd_rn((float)(c0 - 64), 0.5f), 0.2f) - v);
  float d1 = fabsf(__fmul_rn(__fadd_rn((float)(c1 - 64), 0.5f), 0.2f) - v);
  float d2 = fabsf(__fmul_rn(__fadd_rn((float)(c2 - 64), 0.5f), 0.2f) - v);
  int best = c0; float bd = d0;
  if (d1 < bd) { bd = d1; best = c1; }
  if (d2 < bd) { bd = d2; best = c2; }
  return best;
}

// numpy pairwise_sum, exact replication for n=128 (LayerNorm only).
__device__ __forceinline__ float np_pw128(const float* a) {
  float r0=a[0],r1=a[1],r2=a[2],r3=a[3],r4=a[4],r5=a[5],r6=a[6],r7=a[7];
  for (int i = 8; i < 128; i += 8) {
    r0=__fadd_rn(r0,a[i+0]); r1=__fadd_rn(r1,a[i+1]);
    r2=__fadd_rn(r2,a[i+2]); r3=__fadd_rn(r3,a[i+3]);
    r4=__fadd_rn(r4,a[i+4]); r5=__fadd_rn(r5,a[i+5]);
    r6=__fadd_rn(r6,a[i+6]); r7=__fadd_rn(r7,a[i+7]);
  }
  return __fadd_rn(__fadd_rn(__fadd_rn(r0,r1),__fadd_rn(r2,r3)),
                   __fadd_rn(__fadd_rn(r4,r5),__fadd_rn(r6,r7)));
}
__device__ __forceinline__ float np_sum256(const float* a) {
  return __fadd_rn(np_pw128(a), np_pw128(a + 128));
}

__device__ __forceinline__ float sig_np(float x) {
  return __fdiv_rn(1.0f, __fadd_rn(1.0f, expf(-x)));
}

__device__ __forceinline__ void fma4(float& aa, float4 w, float4 v) {
  aa = fmaf(w.x, v.x, aa); aa = fmaf(w.y, v.y, aa);
  aa = fmaf(w.z, v.z, aa); aa = fmaf(w.w, v.w, aa);
}

// Async global->LDS 16B copy: LDS dst = wave-uniform base + lane*16.
__device__ __forceinline__ void gl_lds(const float4* g, float4* l) {
  __builtin_amdgcn_global_load_lds(
      (__attribute__((address_space(1))) void*)g,
      (__attribute__((address_space(3))) void*)l, 16, 0, 0);
}

// Stage one 2048-float4 (32KB) chunk of RA rows into LDS as [kk][row].
// Exactly 2 global_load_lds per wave (32 units of 1KB over 16 waves).
template<int RA>
__device__ __forceinline__ void stage_chunk(float4* dst, const float4* wgT,
                                            const float4* wgO, int k4o,
                                            int Rg, int c0,
                                            int wid, int lane) {
  constexpr int RA64 = RA / 64;
  const int u0 = wid, u1 = wid + 16;
  const int k0 = u0 / RA64, r0 = u0 % RA64;
  const int k1 = u1 / RA64, r1 = u1 % RA64;
  if (wgT) {
    gl_lds(wgT + (size_t)(c0 + k0) * Rg + r0 * 64 + lane, dst + u0 * 64);
    gl_lds(wgT + (size_t)(c0 + k1) * Rg + r1 * 64 + lane, dst + u1 * 64);
  } else {
    gl_lds(wgO + (size_t)(r0 * 64 + lane) * k4o + c0 + k0, dst + u0 * 64);
    gl_lds(wgO + (size_t)(r1 * 64 + lane) * k4o + c0 + k1, dst + u1 * 64);
  }
}

#define MV_COMPUTE(BUF, CIDX)                                        \
  do {                                                               \
    if (tid < RA) {                                                  \
      const float4* sb = wb[BUF];                                    \
      const int cc0 = (CIDX) * CK4;                                  \
      for (int kk = 0; kk < CK4; ++kk)                               \
        fma4(acc, sb[kk * RA + tid], x4[cc0 + kk]);                  \
    }                                                                \
  } while (0)

// Triple-buffered staged matvec, counted vmcnt (2 chunks in flight across
// raw s_barriers). Thread r<RA runs its EXACT ascending fmaf chain.
template<int RA>
__device__ float run_matvec(float4 (*wb)[2048], const float4* wgT,
                            const float4* wgO, int k4o, int Rg, int K4,
                            const float4* x4, int tid, float acc0) {
  constexpr int CK4 = 2048 / RA;   // 8 (RA=256) or 2 (RA=1024)
  const int wid = tid >> 6, lane = tid & 63;
  const int C = K4 / CK4;
  float acc = acc0;
  stage_chunk<RA>(wb[0], wgT, wgO, k4o, Rg, 0, wid, lane);
  if (C > 1) stage_chunk<RA>(wb[1], wgT, wgO, k4o, Rg, CK4, wid, lane);
  int sbuf = 2, cbuf = 0, c = 0;
  for (; c + 2 < C; ++c) {
    stage_chunk<RA>(wb[sbuf], wgT, wgO, k4o, Rg, (c + 2) * CK4, wid, lane);
    asm volatile("s_waitcnt vmcnt(4) lgkmcnt(0)" ::: "memory");
    __builtin_amdgcn_s_barrier();
    MV_COMPUTE(cbuf, c);
    asm volatile("s_waitcnt lgkmcnt(0)" ::: "memory");
    __builtin_amdgcn_s_barrier();
    sbuf = (sbuf == 2) ? 0 : sbuf + 1;
    cbuf = (cbuf == 2) ? 0 : cbuf + 1;
  }
  if (c + 1 < C) {
    asm volatile("s_waitcnt vmcnt(2) lgkmcnt(0)" ::: "memory");
    __builtin_amdgcn_s_barrier();
    MV_COMPUTE(cbuf, c);
    asm volatile("s_waitcnt lgkmcnt(0)" ::: "memory");
    __builtin_amdgcn_s_barrier();
    cbuf = (cbuf == 2) ? 0 : cbuf + 1;
    ++c;
  }
  asm volatile("s_waitcnt vmcnt(0) lgkmcnt(0)" ::: "memory");
  __builtin_amdgcn_s_barrier();
  MV_COMPUTE(cbuf, c);
  asm volatile("s_waitcnt lgkmcnt(0)" ::: "memory");
  __builtin_amdgcn_s_barrier();
  return acc;
}

// ---------------- transpose pre-pass ----------------
struct TransArgs {
  const float* src[9];
  float*       dst[9];
  int          n4[9];      // R*K4 float4 count
  int          rmask[9];   // R-1 (R pow2)
  int          rshift[9];  // log2(R)
  int          K[9];
};

__global__ void transpose_all(TransArgs a) {
  const int gtid = blockIdx.x * blockDim.x + threadIdx.x;
  const int gsz  = gridDim.x * blockDim.x;
  for (int m = 0; m < 9; ++m) {
    const float* __restrict__ src = a.src[m];
    float4* __restrict__ dst = (float4*)a.dst[m];
    const int n = a.n4[m], rm = a.rmask[m], rs = a.rshift[m], K = a.K[m];
    for (int i = gtid; i < n; i += gsz) {
      const int r = i & rm, k4 = i >> rs;
      const float* s = src + (size_t)r * K + (size_t)k4 * 4;
      float4 v; v.x = s[0]; v.y = s[1]; v.z = s[2]; v.w = s[3];
      dst[i] = v;
    }
  }
}

__global__ __launch_bounds__(WGSZ, 4) void planner_kernel(
    const float* __restrict__ inp_start, const float* __restrict__ map_pts,
    const float* __restrict__ ela_w1, const float* __restrict__ ela_w2,
    const float* __restrict__ conv_w, const float* __restrict__ elm_w1,
    const float* __restrict__ elm_w2, const float* __restrict__ ebl_w1,
    const float* __restrict__ ebl_w2, const float* __restrict__ lstm_wih,
    const float* __restrict__ lstm_whh, const float* __restrict__ dm_w1,
    const float* __restrict__ dm_w2, const float* __restrict__ dv_w1,
    const float* __restrict__ dv_w2, const float* __restrict__ wsT,
    int useT, float* __restrict__ g_out) {
  const int b   = blockIdx.x;
  const int tid = threadIdx.x;
  const float4* wsf4 = (const float4*)wsT;

  __shared__ __align__(16) float4 s_wbuf[3][2048];   // 3 x 32KB weight chunks
  __shared__ unsigned s_mask[kGW];
  __shared__ __align__(16) float s_conv[4096];
  __shared__ __align__(16) float s_cw[800];
  __shared__ __align__(16) float s_cat[512];         // [elao | elmo]
  __shared__ __align__(16) float s_elah[kH], s_elmh[kH], s_eblh[kH], s_eblo[kH];
  __shared__ __align__(16) float s_h0[kH], s_c0[kH], s_h1[kH], s_c1[kH];
  __shared__ __align__(16) float s_gate[1024];
  __shared__ __align__(16) float s_tmp[512];
  __shared__ __align__(16) float s_r[kH], s_dmh[kH], s_dvh[kH];
  __shared__ __align__(16) float s_ones[kH];
  __shared__ __align__(16) float s_hw[1536];         // dm_w2|dv_w2 st slices
  __shared__ float s_anchor[3], s_cs[2], s_g6[6];
  __shared__ float s_mu, s_den;

  // ---- init ----
  if (tid == 0) {
    float a2 = inp_start[b * 3 + 2];
    s_anchor[0] = inp_start[b * 3 + 0];
    s_anchor[1] = inp_start[b * 3 + 1];
    s_anchor[2] = a2;
    s_cs[0] = (float)cos((double)a2);
    s_cs[1] = (float)sin((double)a2);
  }
  if (tid < kH) s_ones[tid] = 1.0f;
  if (tid < 3) {
    g_out[b * 96 + tid] = inp_start[b * 3 + tid];
    g_out[6144 + b * 96 + tid] = 0.01f;
  }
  __syncthreads();

  for (int k = 0; k < 28; ++k) {
    const int st = k / 7, a = k % 7;
    const bool a0f = (a == 0);

    // ---- phase 1: mask clear, conv-w stage, ela hidden (K=3) ----
    if (tid < kGW) s_mask[tid] = 0u;
    if (tid < 800) s_cw[tid] = conv_w[st * 800 + tid];
    if (tid >= 768 && tid < 768 + kH) {
      const int r = tid - 768;
      const float* w1r = ela_w1 + (st * kH + r) * 3;
      float h = fmaf(s_anchor[2], w1r[2],
                fmaf(s_anchor[1], w1r[1], __fmul_rn(s_anchor[0], w1r[0])));
      s_elah[r] = fmaxf(h, 0.0f);
    }
    __syncthreads();

    // ---- phase 2: OGM scatter ----
    {
      float ax = s_anchor[0], ay = s_anchor[1], cc = s_cs[0], ss = s_cs[1];
      for (int n = tid; n < kN; n += WGSZ) {
        float mx = __fadd_rn(map_pts[n],      -ax);
        float my = __fadd_rn(map_pts[kN + n], -ay);
        float px = fmaf(ss, my, __fmul_rn(cc, mx));
        float py = fmaf(cc, my, -__fmul_rn(ss, mx));
        bool outb = (fabsf(px) > 12.8f) || (fabsf(py) > 12.8f);
        px = outb ? 0.0f : px;
        py = outb ? 0.0f : py;
        int xi = bin_idx(px), yi = bin_idx(py);
        atomicOr(&s_mask[xi * 4 + (yi >> 5)], 1u << (yi & 31));
      }
    }
    __syncthreads();

    // ---- phase 3: conv 5x5/s2, EXACT baseline (o,ci,t) chain order ----
    for (int q = 0; q < 4; ++q) {
      const int p = tid + (q << 10);
      const int oy = p >> 6, ox = p & 63;
      unsigned occ = 0u;
      for (int ky = 0; ky < 5; ++ky) {
        const int y = 2 * oy - 2 + ky;
        if ((unsigned)y >= 128u) continue;
        const unsigned* row = &s_mask[y * 4];
        for (int kx = 0; kx < 5; ++kx) {
          const int x = 2 * ox - 2 + kx;
          if ((unsigned)x >= 128u) continue;
          if ((row[x >> 5] >> (x & 31)) & 1u) occ |= 1u << (ky * 5 + kx);
        }
      }
      float csum = 0.0f;
      if (occ != 0u) {
        for (int o = 0; o < 8; ++o) {
          float acc = 0.0f;
          const float* wo = s_cw + o * 100;
          for (int ci = 0; ci < 4; ++ci) {
            const float* wc = wo + ci * 25;
            #pragma unroll
            for (int t = 0; t < 25; ++t)
              acc = __fadd_rn(acc, ((occ >> t) & 1u) ? wc[t] : 0.0f);
          }
          float th = tanhf(acc);
          csum = (o == 0) ? th : __fadd_rn(csum, th);
        }
      }
      s_conv[p] = csum;
    }
    __syncthreads();

    // ---- phase 4: ela out (staged) -> s_cat[0:256] ----
    {
      const float4* wT = useT ? wsf4 + OFF_ELA2 / 4 + st * 256 : nullptr;
      const float4* wO = useT ? nullptr
                              : (const float4*)ela_w2 + (size_t)(st * 256) * 64;
      float acc = run_matvec<256>(s_wbuf, wT, wO, 64, 1024, 64,
                                  (const float4*)s_elah, tid, 0.0f);
      if (tid < kH) s_cat[tid] = acc;
    }

    // ---- phase 5: elm hidden (K=4096, staged) ----
    {
      const float4* wT = useT ? wsf4 + OFF_ELM1 / 4 + st * 256 : nullptr;
      const float4* wO = useT ? nullptr
                              : (const float4*)elm_w1 + (size_t)(st * 256) * 1024;
      float acc = run_matvec<256>(s_wbuf, wT, wO, 1024, 1024, 1024,
                                  (const float4*)s_conv, tid, 0.0f);
      if (tid < kH) s_elmh[tid] = fmaxf(acc, 0.0f);
    }

    // ---- phase 6: elm out -> s_cat[256:512] ----
    {
      const float4* wT = useT ? wsf4 + OFF_ELM2 / 4 + st * 256 : nullptr;
      const float4* wO = useT ? nullptr
                              : (const float4*)elm_w2 + (size_t)(st * 256) * 64;
      float acc = run_matvec<256>(s_wbuf, wT, wO, 64, 1024, 64,
                                  (const float4*)s_elmh, tid, 0.0f);
      if (tid < kH) s_cat[256 + tid] = acc;
    }

    // ---- phase 7: ebl hidden (K=512 over concat) ----
    {
      const float4* wT = useT ? wsf4 + OFF_EBL1 / 4 + st * 256 : nullptr;
      const float4* wO = useT ? nullptr
                              : (const float4*)ebl_w1 + (size_t)(st * 256) * 128;
      float acc = run_matvec<256>(s_wbuf, wT, wO, 128, 1024, 128,
                                  (const float4*)s_cat, tid, 0.0f);
      if (tid < kH) s_eblh[tid] = fmaxf(acc, 0.0f);
    }

    // ---- phase 8: ebl out ----
    {
      const float4* wT = useT ? wsf4 + OFF_EBL2 / 4 + st * 256 : nullptr;
      const float4* wO = useT ? nullptr
                              : (const float4*)ebl_w2 + (size_t)(st * 256) * 64;
      float acc = run_matvec<256>(s_wbuf, wT, wO, 64, 1024, 64,
                                  (const float4*)s_eblh, tid, 0.0f);
      if (tid < kH) s_eblo[tid] = acc;
    }

    // ---- LSTM layers: A-chain(wih) + B-chain(whh), 1024 rows/thread ----
    for (int l = 0; l < 2; ++l) {
      const int rowbase = (st * 2 + l) * 1024;
      const float* xe = (l == 0) ? s_eblo : s_h0;
      const float* xh = a0f ? s_ones : ((l == 0) ? s_h0 : s_h1);
      float accA, accB;
      {
        const float4* wT = useT ? wsf4 + OFF_WIH / 4 + rowbase : nullptr;
        const float4* wO = useT ? nullptr
                                : (const float4*)lstm_wih + (size_t)rowbase * 64;
        accA = run_matvec<1024>(s_wbuf, wT, wO, 64, 8192, 64,
                                (const float4*)xe, tid, 0.0f);
      }
      {
        const float4* wT = useT ? wsf4 + OFF_WHH / 4 + rowbase : nullptr;
        const float4* wO = useT ? nullptr
                                : (const float4*)lstm_whh + (size_t)rowbase * 64;
        accB = run_matvec<1024>(s_wbuf, wT, wO, 64, 8192, 64,
                                (const float4*)xh, tid, 0.0f);
      }
      s_gate[tid] = __fadd_rn(accA, accB);
      __syncthreads();
      if (tid < kH) {
        float gi = s_gate[tid], gf = s_gate[256 + tid];
        float gg = s_gate[512 + tid], go = s_gate[768 + tid];
        float* sc = (l == 0) ? s_c0 : s_c1;
        float* sh = (l == 0) ? s_h0 : s_h1;
        float cprev = a0f ? 1.0f : sc[tid];
        float cl = __fadd_rn(__fmul_rn(sig_np(gf), cprev),
                             __fmul_rn(sig_np(gi), tanhf(gg)));
        float hl = __fmul_rn(sig_np(go), tanhf(cl));
        sc[tid] = cl; sh[tid] = hl;
      }
      __syncthreads();
    }

    // ---- stage head weights (used later) + LayerNorm ----
    if (tid < 1536)
      s_hw[tid] = (tid < 768) ? dm_w2[st * 768 + tid]
                              : dv_w2[st * 768 + tid - 768];
    if (tid == 0) s_mu = __fdiv_rn(np_sum256(s_h1), 256.0f);
    __syncthreads();
    if (tid < kH) {
      float d = __fadd_rn(s_h1[tid], -s_mu);
      s_tmp[tid] = d;
      s_tmp[256 + tid] = __fmul_rn(d, d);
    }
    __syncthreads();
    if (tid == 0) {
      float v = __fdiv_rn(np_sum256(s_tmp + 256), 256.0f);
      s_den = __fsqrt_rn(__fadd_rn(v, 1e-5f));
    }
    __syncthreads();
    if (tid < kH) {
      float r = __fadd_rn(__fdiv_rn(s_tmp[tid], s_den), s_eblo[tid]);
      s_r[tid] = fmaxf(r, 0.0f);
    }
    __syncthreads();

    // ---- dm / dv hidden (staged) ----
    {
      const float4* wT = useT ? wsf4 + OFF_DM1 / 4 + st * 256 : nullptr;
      const float4* wO = useT ? nullptr
                              : (const float4*)dm_w1 + (size_t)(st * 256) * 64;
      float acc = run_matvec<256>(s_wbuf, wT, wO, 64, 1024, 64,
                                  (const float4*)s_r, tid, 0.0f);
      if (tid < kH) s_dmh[tid] = fmaxf(acc, 0.0f);
    }
    {
      const float4* wT = useT ? wsf4 + OFF_DV1 / 4 + st * 256 : nullptr;
      const float4* wO = useT ? nullptr
                              : (const float4*)dv_w1 + (size_t)(st * 256) * 64;
      float acc = run_matvec<256>(s_wbuf, wT, wO, 64, 1024, 64,
                                  (const float4*)s_r, tid, 0.0f);
      if (tid < kH) s_dvh[tid] = fmaxf(acc, 0.0f);
    }
    __syncthreads();

    // ---- heads: 6 rows, exact ascending chains from LDS ----
    if (tid < 6) {
      const int d = tid % 3; const bool isv = tid >= 3;
      const float4* w4 = (const float4*)(s_hw + (isv ? 768 : 0) + d * 256);
      const float4* xx = (const float4*)(isv ? s_dvh : s_dmh);
      float acc = 0.0f;
      for (int i = 0; i < 64; ++i) fma4(acc, w4[i], xx[i]);
      s_g6[tid] = acc;
    }
    __syncthreads();

    // ---- anchor update + outputs ----
    if (tid == 0) {
      const float dlmf[3] = {2.0f, 2.0f, 0.5f};
      for (int d = 0; d < 3; ++d) {
        float avn = __fadd_rn(s_anchor[d], __fmul_rn(tanhf(s_g6[d]), dlmf[d]));
        float vvn = __fmul_rn(sig_np(s_g6[3 + d]), 0.1f);
        s_anchor[d] = avn;
        int o = ((b * 4 + st) * 8 + (a + 1)) * 3 + d;
        g_out[o] = avn;
        g_out[6144 + o] = vvn;
        if (a == 6 && st < 3) {
          int o2 = ((b * 4 + st + 1) * 8 + 0) * 3 + d;
          g_out[o2] = avn;
          g_out[6144 + o2] = vvn;
        }
      }
      s_cs[0] = (float)cos((double)s_anchor[2]);
      s_cs[1] = (float)sin((double)s_anchor[2]);
    }
    __syncthreads();
  }
}

extern "C" void kernel_launch(void* const* d_in, const int* in_sizes, int n_in,
                              void* d_out, int out_size, void* d_ws, size_t ws_size,
                              hipStream_t stream) {
  (void)in_sizes; (void)n_in; (void)out_size;
  const int useT = (d_ws != nullptr && ws_size >= WS_FLOATS * sizeof(float)) ? 1 : 0;
  float* wsf = (float*)d_ws;

  if (useT) {
    TransArgs ta;
    const float* srcs[9] = {
        (const float*)d_in[3],  (const float*)d_in[5],  (const float*)d_in[6],
        (const float*)d_in[7],  (const float*)d_in[8],  (const float*)d_in[11],
        (const float*)d_in[13], (const float*)d_in[9],  (const float*)d_in[10]};
    float* dsts[9] = {
        wsf + OFF_ELA2, wsf + OFF_ELM1, wsf + OFF_ELM2, wsf + OFF_EBL1,
        wsf + OFF_EBL2, wsf + OFF_DM1,  wsf + OFF_DV1,  wsf + OFF_WIH,
        wsf + OFF_WHH};
    const int n4s[9] = {65536, 1048576, 65536, 131072, 65536, 65536, 65536,
                        524288, 524288};
    const int rms[9] = {1023, 1023, 1023, 1023, 1023, 1023, 1023, 8191, 8191};
    const int rss[9] = {10, 10, 10, 10, 10, 10, 10, 13, 13};
    const int Ks[9]  = {256, 4096, 256, 512, 256, 256, 256, 256, 256};
    for (int m = 0; m < 9; ++m) {
      ta.src[m] = srcs[m]; ta.dst[m] = dsts[m]; ta.n4[m] = n4s[m];
      ta.rmask[m] = rms[m]; ta.rshift[m] = rss[m]; ta.K[m] = Ks[m];
    }
    transpose_all<<<dim3(1024), dim3(256), 0, stream>>>(ta);
  }

  planner_kernel<<<dim3(NWG), dim3(WGSZ), 0, stream>>>(
      (const float*)d_in[0],  (const float*)d_in[1],  (const float*)d_in[2],
      (const float*)d_in[3],  (const float*)d_in[4],  (const float*)d_in[5],
      (const float*)d_in[6],  (const float*)d_in[7],  (const float*)d_in[8],
      (const float*)d_in[9],  (const float*)d_in[10], (const float*)d_in[11],
      (const float*)d_in[12], (const float*)d_in[13], (const float*)d_in[14],
      (const float*)wsf, useT, (float*)d_out);
}

// Round 10
// 8289.291 us; speedup vs baseline: 1.3065x; 1.3065x over previous
//
#include <hip/hip_runtime.h>

#define WGSZ 1024
#define NWG  256

namespace {
constexpr int kN = 2048, kH = 256, kGW = 512;
// workspace layout (floats)
constexpr size_t OFF_ITM = 16384;                 // after 16384 uint counters
constexpr size_t OFF_W0  = OFF_ITM + 64 * 4096;   // transposed weights base
// transposed-weight offsets relative to OFF_W0 (floats); layout [k4][row] f4
constexpr size_t TO_ELA2 = 0;
constexpr size_t TO_ELM1 = 262144;
constexpr size_t TO_ELM2 = 4456448;
constexpr size_t TO_EBL1 = 4718592;
constexpr size_t TO_EBL2 = 5242880;
constexpr size_t TO_DM1  = 5505024;
constexpr size_t TO_DV1  = 5767168;
constexpr size_t TO_WIH  = 6029312;
constexpr size_t TO_WHH  = 8126464;
constexpr size_t W_FLOATS = 10223616;
constexpr size_t WS_FULL  = OFF_W0 + W_FLOATS;    // ~42 MB
// per-batch intermediate offsets (floats)
constexpr int I_CAT = 0, I_ELMH = 512, I_EBLH = 768, I_EBLO = 1024,
              I_G0 = 1280, I_G1 = 2304, I_DMH = 3328, I_DVH = 3584;
}

__device__ __forceinline__ int bin_idx(float v) {
  float t = fmaf(v, 5.0f, 63.5f);
  int i0 = (int)floorf(t);
  int c0 = i0 - 1; c0 = c0 < 0 ? 0 : (c0 > 127 ? 127 : c0);
  int c1 = i0;     c1 = c1 < 0 ? 0 : (c1 > 127 ? 127 : c1);
  int c2 = i0 + 1; c2 = c2 < 0 ? 0 : (c2 > 127 ? 127 : c2);
  float d0 = fabsf(__fmul_rn(__fadd_rn((float)(c0 - 64), 0.5f), 0.2f) - v);
  float d1 = fabsf(__fmul_rn(__fadd_rn((float)(c1 - 64), 0.5f), 0.2f) - v);
  float d2 = fabsf(__fmul_rn(__fadd_rn((float)(c2 - 64), 0.5f), 0.2f) - v);
  int best = c0; float bd = d0;
  if (d1 < bd) { bd = d1; best = c1; }
  if (d2 < bd) { bd = d2; best = c2; }
  return best;
}

__device__ __forceinline__ float np_pw128(const float* a) {
  float r0=a[0],r1=a[1],r2=a[2],r3=a[3],r4=a[4],r5=a[5],r6=a[6],r7=a[7];
  for (int i = 8; i < 128; i += 8) {
    r0=__fadd_rn(r0,a[i+0]); r1=__fadd_rn(r1,a[i+1]);
    r2=__fadd_rn(r2,a[i+2]); r3=__fadd_rn(r3,a[i+3]);
    r4=__fadd_rn(r4,a[i+4]); r5=__fadd_rn(r5,a[i+5]);
    r6=__fadd_rn(r6,a[i+6]); r7=__fadd_rn(r7,a[i+7]);
  }
  return __fadd_rn(__fadd_rn(__fadd_rn(r0,r1),__fadd_rn(r2,r3)),
                   __fadd_rn(__fadd_rn(r4,r5),__fadd_rn(r6,r7)));
}
__device__ __forceinline__ float np_sum256(const float* a) {
  return __fadd_rn(np_pw128(a), np_pw128(a + 128));
}

__device__ __forceinline__ float sig_np(float x) {
  return __fdiv_rn(1.0f, __fadd_rn(1.0f, expf(-x)));
}

__device__ __forceinline__ void fma4(float& aa, float4 w, float4 v) {
  aa = fmaf(w.x, v.x, aa); aa = fmaf(w.y, v.y, aa);
  aa = fmaf(w.z, v.z, aa); aa = fmaf(w.w, v.w, aa);
}

__device__ __forceinline__ void gl_lds(const float4* g, float4* l) {
  __builtin_amdgcn_global_load_lds(
      (__attribute__((address_space(1))) void*)g,
      (__attribute__((address_space(3))) void*)l, 16, 0, 0);
}

// Cross-WG barrier among the 4 WGs of one batch. Fresh counter per sync point
// (zeroed by prep kernel). Agent-scope release/acquire handles XCD L2s.
__device__ __forceinline__ void bat_bar(unsigned* cnt, int tid) {
  __syncthreads();
  if (tid == 0) {
    __threadfence();
    __hip_atomic_fetch_add(cnt, 1u, __ATOMIC_RELEASE, __HIP_MEMORY_SCOPE_AGENT);
    while (__hip_atomic_load(cnt, __ATOMIC_ACQUIRE,
                             __HIP_MEMORY_SCOPE_AGENT) < 4u)
      __builtin_amdgcn_s_sleep(1);
  }
  __syncthreads();
}

// Row-split staged matvec: this WG computes RW rows starting at global row G0.
// Chunk = 1024 float4 (16KB) as [CK4][RW]; 1 global_load_lds per wave per
// chunk; 6 LDS buffers, prefetch depth 4, counted vmcnt, 1 barrier/chunk.
// Thread tid<RW runs its EXACT ascending-k fmaf chain.
#define MV_STAGE(CI, BI)                                                       \
  do {                                                                         \
    float4* dst = wb[BI] + wid * 64;                                           \
    const int cs0 = (CI) * CK4;                                                \
    if (wT) gl_lds(wT + (size_t)(cs0 + k4l) * Rg + G0 + sub * 64 + lane, dst); \
    else    gl_lds(wO + (size_t)(G0 + sub * 64 + lane) * k4o + cs0 + k4l, dst);\
  } while (0)

#define MV_COMP(BI, CI)                                                        \
  do {                                                                         \
    if (tid < RW) {                                                            \
      const float4* sb = wb[BI];                                               \
      const int cc0 = (CI) * CK4;                                              \
      for (int kk = 0; kk < CK4; ++kk)                                         \
        fma4(acc, sb[kk * RW + tid], x4[cc0 + kk]);                            \
    }                                                                          \
  } while (0)

template<int RW>
__device__ float mv_split(float4 (*wb)[1024], const float4* wT,
                          const float4* wO, int k4o, int Rg, int K4, int G0,
                          const float4* x4, int tid, float acc0) {
  constexpr int RW64 = RW / 64;     // 1 or 4
  constexpr int CK4  = 16 / RW64;   // 16 or 4
  const int C = K4 / CK4;           // >= 4 for all phases
  const int wid = tid >> 6, lane = tid & 63;
  const int k4l = wid / RW64, sub = wid - k4l * RW64;
  float acc = acc0;
  MV_STAGE(0, 0);
  MV_STAGE(1, 1);
  MV_STAGE(2, 2);
  MV_STAGE(3, 3);
  int c = 0, cbuf = 0, sbuf = 4;
  for (; c + 4 < C; ++c) {
    MV_STAGE(c + 4, sbuf);
    asm volatile("s_waitcnt vmcnt(4)" ::: "memory");
    __builtin_amdgcn_s_barrier();
    MV_COMP(cbuf, c);
    sbuf = (sbuf == 5) ? 0 : sbuf + 1;
    cbuf = (cbuf == 5) ? 0 : cbuf + 1;
  }
  asm volatile("s_waitcnt vmcnt(3)" ::: "memory");
  __builtin_amdgcn_s_barrier();
  MV_COMP(cbuf, c);
  cbuf = (cbuf == 5) ? 0 : cbuf + 1; ++c;
  asm volatile("s_waitcnt vmcnt(2)" ::: "memory");
  __builtin_amdgcn_s_barrier();
  MV_COMP(cbuf, c);
  cbuf = (cbuf == 5) ? 0 : cbuf + 1; ++c;
  asm volatile("s_waitcnt vmcnt(1)" ::: "memory");
  __builtin_amdgcn_s_barrier();
  MV_COMP(cbuf, c);
  cbuf = (cbuf == 5) ? 0 : cbuf + 1; ++c;
  asm volatile("s_waitcnt vmcnt(0)" ::: "memory");
  __builtin_amdgcn_s_barrier();
  MV_COMP(cbuf, c);
  __syncthreads();
  return acc;
}

// ---------------- prep: zero barrier counters + transpose weights ----------
struct TransArgs {
  const float* src[9];
  float*       dst[9];
  int          n4[9];
  int          rmask[9];
  int          rshift[9];
  int          K[9];
};

__global__ void prep_kernel(TransArgs a, unsigned* bar, int nmat) {
  const int gtid = blockIdx.x * blockDim.x + threadIdx.x;
  const int gsz  = gridDim.x * blockDim.x;
  for (int i = gtid; i < 16384; i += gsz) bar[i] = 0u;
  for (int m = 0; m < nmat; ++m) {
    const float* __restrict__ src = a.src[m];
    float4* __restrict__ dst = (float4*)a.dst[m];
    const int n = a.n4[m], rm = a.rmask[m], rs = a.rshift[m], K = a.K[m];
    for (int i = gtid; i < n; i += gsz) {
      const int r = i & rm, k4 = i >> rs;
      const float* s = src + (size_t)r * K + (size_t)k4 * 4;
      float4 v; v.x = s[0]; v.y = s[1]; v.z = s[2]; v.w = s[3];
      dst[i] = v;
    }
  }
}

// 256 WGs (plain launch, 1 WG/CU -> all resident). blockIdx = b*4+g.
// WG g owns rows [g*64,..) (gates [g*256,..)).
__global__ __launch_bounds__(WGSZ, 4) void planner_kernel(
    const float* __restrict__ inp_start, const float* __restrict__ map_pts,
    const float* __restrict__ ela_w1, const float* __restrict__ ela_w2,
    const float* __restrict__ conv_w, const float* __restrict__ elm_w1,
    const float* __restrict__ elm_w2, const float* __restrict__ ebl_w1,
    const float* __restrict__ ebl_w2, const float* __restrict__ lstm_wih,
    const float* __restrict__ lstm_whh, const float* __restrict__ dm_w1,
    const float* __restrict__ dm_w2, const float* __restrict__ dv_w1,
    const float* __restrict__ dv_w2, float* __restrict__ ws,
    int useT, float* __restrict__ g_out) {
  const int b   = blockIdx.x >> 2;
  const int g   = blockIdx.x & 3;
  const int tid = threadIdx.x;
  float* itm = ws + OFF_ITM + (size_t)b * 4096;
  unsigned* barp = (unsigned*)ws + (size_t)b * 256;
  const float4* wsW = (const float4*)(ws + OFF_W0);

  __shared__ __align__(16) float4 s_wbuf[6][1024];   // 6 x 16KB chunks
  __shared__ unsigned s_mask[kGW];
  __shared__ __align__(16) float s_conv[4096];
  __shared__ __align__(16) float s_cw[800];
  __shared__ __align__(16) float s_elah[kH];
  __shared__ __align__(16) float s_xa[512];
  __shared__ __align__(16) float s_eblo[kH];
  __shared__ __align__(16) float s_r[kH];
  __shared__ __align__(16) float s_gate[1024];
  __shared__ __align__(16) float s_h0[kH], s_c0[kH], s_h1[kH], s_c1[kH];
  __shared__ __align__(16) float s_ones[kH];
  __shared__ __align__(16) float s_tmp[512];
  __shared__ __align__(16) float s_hw[1536];
  __shared__ float s_anchor[3], s_cs[2], s_g6[6];
  __shared__ float s_mu, s_den;

  if (tid == 0) {
    float a2 = inp_start[b * 3 + 2];
    s_anchor[0] = inp_start[b * 3 + 0];
    s_anchor[1] = inp_start[b * 3 + 1];
    s_anchor[2] = a2;
    s_cs[0] = (float)cos((double)a2);
    s_cs[1] = (float)sin((double)a2);
  }
  if (tid < kH) s_ones[tid] = 1.0f;
  if (g == 0 && tid < 3) {
    g_out[b * 96 + tid] = inp_start[b * 3 + tid];
    g_out[6144 + b * 96 + tid] = 0.01f;
  }
  __syncthreads();

  int sidx = 0;
  for (int k = 0; k < 28; ++k) {
    const int st = k / 7, a = k % 7;
    const bool a0f = (a == 0);

    // ---- replicated: mask clear, conv-w stage, ela hidden (K=3) ----
    if (tid < kGW) s_mask[tid] = 0u;
    if (tid < 800) s_cw[tid] = conv_w[st * 800 + tid];
    if (tid < kH) {
      const float* w1r = ela_w1 + (st * kH + tid) * 3;
      float h = fmaf(s_anchor[2], w1r[2],
                fmaf(s_anchor[1], w1r[1], __fmul_rn(s_anchor[0], w1r[0])));
      s_elah[tid] = fmaxf(h, 0.0f);
    }
    if (tid < 1536)
      s_hw[tid] = (tid < 768) ? dm_w2[st * 768 + tid]
                              : dv_w2[st * 768 + tid - 768];
    __syncthreads();

    // ---- replicated: OGM scatter ----
    {
      float ax = s_anchor[0], ay = s_anchor[1], cc = s_cs[0], ss = s_cs[1];
      for (int n = tid; n < kN; n += WGSZ) {
        float mx = __fadd_rn(map_pts[n],      -ax);
        float my = __fadd_rn(map_pts[kN + n], -ay);
        float px = fmaf(ss, my, __fmul_rn(cc, mx));
        float py = fmaf(cc, my, -__fmul_rn(ss, mx));
        bool outb = (fabsf(px) > 12.8f) || (fabsf(py) > 12.8f);
        px = outb ? 0.0f : px;
        py = outb ? 0.0f : py;
        int xi = bin_idx(px), yi = bin_idx(py);
        atomicOr(&s_mask[xi * 4 + (yi >> 5)], 1u << (yi & 31));
      }
    }
    __syncthreads();

    // ---- replicated: conv 5x5/s2, EXACT (o,ci,t) chain order ----
    for (int q = 0; q < 4; ++q) {
      const int p = tid + (q << 10);
      const int oy = p >> 6, ox = p & 63;
      unsigned occ = 0u;
      for (int ky = 0; ky < 5; ++ky) {
        const int y = 2 * oy - 2 + ky;
        if ((unsigned)y >= 128u) continue;
        const unsigned* row = &s_mask[y * 4];
        for (int kx = 0; kx < 5; ++kx) {
          const int x = 2 * ox - 2 + kx;
          if ((unsigned)x >= 128u) continue;
          if ((row[x >> 5] >> (x & 31)) & 1u) occ |= 1u << (ky * 5 + kx);
        }
      }
      float csum = 0.0f;
      if (occ != 0u) {
        for (int o = 0; o < 8; ++o) {
          float acc = 0.0f;
          const float* wo = s_cw + o * 100;
          for (int ci = 0; ci < 4; ++ci) {
            const float* wc = wo + ci * 25;
            #pragma unroll
            for (int t = 0; t < 25; ++t)
              acc = __fadd_rn(acc, ((occ >> t) & 1u) ? wc[t] : 0.0f);
          }
          float th = tanhf(acc);
          csum = (o == 0) ? th : __fadd_rn(csum, th);
        }
      }
      s_conv[p] = csum;
    }
    __syncthreads();

    const int G64 = st * 256 + g * 64;

    // ---- S1: elao (rows/4) + elmh (rows/4) ----
    {
      float acc = mv_split<64>(s_wbuf, useT ? wsW + TO_ELA2 / 4 : nullptr,
                               (const float4*)ela_w2, 64, 1024, 64, G64,
                               (const float4*)s_elah, tid, 0.0f);
      if (tid < 64) itm[I_CAT + g * 64 + tid] = acc;
      acc = mv_split<64>(s_wbuf, useT ? wsW + TO_ELM1 / 4 : nullptr,
                         (const float4*)elm_w1, 1024, 1024, 1024, G64,
                         (const float4*)s_conv, tid, 0.0f);
      if (tid < 64) itm[I_ELMH + g * 64 + tid] = fmaxf(acc, 0.0f);
    }
    bat_bar(barp + sidx, tid); ++sidx;

    // ---- S2: elmo ----
    if (tid < kH) s_xa[tid] = itm[I_ELMH + tid];
    __syncthreads();
    {
      float acc = mv_split<64>(s_wbuf, useT ? wsW + TO_ELM2 / 4 : nullptr,
                               (const float4*)elm_w2, 64, 1024, 64, G64,
                               (const float4*)s_xa, tid, 0.0f);
      if (tid < 64) itm[I_CAT + 256 + g * 64 + tid] = acc;
    }
    bat_bar(barp + sidx, tid); ++sidx;

    // ---- S3: eblh (K=512 over concat) ----
    if (tid < 512) s_xa[tid] = itm[I_CAT + tid];
    __syncthreads();
    {
      float acc = mv_split<64>(s_wbuf, useT ? wsW + TO_EBL1 / 4 : nullptr,
                               (const float4*)ebl_w1, 128, 1024, 128, G64,
                               (const float4*)s_xa, tid, 0.0f);
      if (tid < 64) itm[I_EBLH + g * 64 + tid] = fmaxf(acc, 0.0f);
    }
    bat_bar(barp + sidx, tid); ++sidx;

    // ---- S4: eblo ----
    if (tid < kH) s_xa[tid] = itm[I_EBLH + tid];
    __syncthreads();
    {
      float acc = mv_split<64>(s_wbuf, useT ? wsW + TO_EBL2 / 4 : nullptr,
                               (const float4*)ebl_w2, 64, 1024, 64, G64,
                               (const float4*)s_xa, tid, 0.0f);
      if (tid < 64) itm[I_EBLO + g * 64 + tid] = acc;
    }
    bat_bar(barp + sidx, tid); ++sidx;

    // ---- S5/S6: LSTM layers, gates rows [g*256,(g+1)*256) ----
    if (tid < kH) s_eblo[tid] = itm[I_EBLO + tid];
    __syncthreads();
    for (int l = 0; l < 2; ++l) {
      const int rowb = (st * 2 + l) * 1024 + g * 256;
      const float* xe = (l == 0) ? s_eblo : s_h0;
      const float* xh = a0f ? s_ones : ((l == 0) ? s_h0 : s_h1);
      float accA = mv_split<256>(s_wbuf, useT ? wsW + TO_WIH / 4 : nullptr,
                                 (const float4*)lstm_wih, 64, 8192, 64, rowb,
                                 (const float4*)xe, tid, 0.0f);
      float accB = mv_split<256>(s_wbuf, useT ? wsW + TO_WHH / 4 : nullptr,
                                 (const float4*)lstm_whh, 64, 8192, 64, rowb,
                                 (const float4*)xh, tid, 0.0f);
      const int IG = (l == 0) ? I_G0 : I_G1;
      if (tid < kH) itm[IG + g * 256 + tid] = __fadd_rn(accA, accB);
      bat_bar(barp + sidx, tid); ++sidx;
      s_gate[tid] = itm[IG + tid];
      __syncthreads();
      if (tid < kH) {
        float gi = s_gate[tid], gf = s_gate[256 + tid];
        float gg = s_gate[512 + tid], go = s_gate[768 + tid];
        float* sc = (l == 0) ? s_c0 : s_c1;
        float* sh = (l == 0) ? s_h0 : s_h1;
        float cprev = a0f ? 1.0f : sc[tid];
        float cl = __fadd_rn(__fmul_rn(sig_np(gf), cprev),
                             __fmul_rn(sig_np(gi), tanhf(gg)));
        float hl = __fmul_rn(sig_np(go), tanhf(cl));
        sc[tid] = cl; sh[tid] = hl;
      }
      __syncthreads();
    }

    // ---- replicated: LayerNorm + r ----
    if (tid == 0) s_mu = __fdiv_rn(np_sum256(s_h1), 256.0f);
    __syncthreads();
    if (tid < kH) {
      float d = __fadd_rn(s_h1[tid], -s_mu);
      s_tmp[tid] = d;
      s_tmp[256 + tid] = __fmul_rn(d, d);
    }
    __syncthreads();
    if (tid == 0) {
      float v = __fdiv_rn(np_sum256(s_tmp + 256), 256.0f);
      s_den = __fsqrt_rn(__fadd_rn(v, 1e-5f));
    }
    __syncthreads();
    if (tid < kH) {
      float r = __fadd_rn(__fdiv_rn(s_tmp[tid], s_den), s_eblo[tid]);
      s_r[tid] = fmaxf(r, 0.0f);
    }
    __syncthreads();

    // ---- S7: dm/dv hidden (rows/4 each) ----
    {
      float acc = mv_split<64>(s_wbuf, useT ? wsW + TO_DM1 / 4 : nullptr,
                               (const float4*)dm_w1, 64, 1024, 64, G64,
                               (const float4*)s_r, tid, 0.0f);
      if (tid < 64) itm[I_DMH + g * 64 + tid] = fmaxf(acc, 0.0f);
      acc = mv_split<64>(s_wbuf, useT ? wsW + TO_DV1 / 4 : nullptr,
                         (const float4*)dv_w1, 64, 1024, 64, G64,
                         (const float4*)s_r, tid, 0.0f);
      if (tid < 64) itm[I_DVH + g * 64 + tid] = fmaxf(acc, 0.0f);
    }
    bat_bar(barp + sidx, tid); ++sidx;

    // ---- replicated: heads + anchor update ----
    if (tid < 512)
      s_xa[tid] = (tid < 256) ? itm[I_DMH + tid] : itm[I_DVH + tid - 256];
    __syncthreads();
    if (tid < 6) {
      const int d = tid % 3; const bool isv = tid >= 3;
      const float4* w4 = (const float4*)(s_hw + (isv ? 768 : 0) + d * 256);
      const float4* xx = (const float4*)(isv ? s_xa + 256 : s_xa);
      float acc = 0.0f;
      for (int i = 0; i < 64; ++i) fma4(acc, w4[i], xx[i]);
      s_g6[tid] = acc;
    }
    __syncthreads();
    if (tid == 0) {
      const float dlmf[3] = {2.0f, 2.0f, 0.5f};
      for (int d = 0; d < 3; ++d) {
        float avn = __fadd_rn(s_anchor[d], __fmul_rn(tanhf(s_g6[d]), dlmf[d]));
        float vvn = __fmul_rn(sig_np(s_g6[3 + d]), 0.1f);
        s_anchor[d] = avn;
        if (g == 0) {
          int o = ((b * 4 + st) * 8 + (a + 1)) * 3 + d;
          g_out[o] = avn;
          g_out[6144 + o] = vvn;
          if (a == 6 && st < 3) {
            int o2 = ((b * 4 + st + 1) * 8 + 0) * 3 + d;
            g_out[o2] = avn;
            g_out[6144 + o2] = vvn;
          }
        }
      }
      s_cs[0] = (float)cos((double)s_anchor[2]);
      s_cs[1] = (float)sin((double)s_anchor[2]);
    }
    __syncthreads();
  }
}

extern "C" void kernel_launch(void* const* d_in, const int* in_sizes, int n_in,
                              void* d_out, int out_size, void* d_ws, size_t ws_size,
                              hipStream_t stream) {
  (void)in_sizes; (void)n_in; (void)out_size;
  float* wsf = (float*)d_ws;
  const int useT = (ws_size >= WS_FULL * sizeof(float)) ? 1 : 0;

  TransArgs ta;
  const float* srcs[9] = {
      (const float*)d_in[3],  (const float*)d_in[5],  (const float*)d_in[6],
      (const float*)d_in[7],  (const float*)d_in[8],  (const float*)d_in[11],
      (const float*)d_in[13], (const float*)d_in[9],  (const float*)d_in[10]};
  float* w0 = wsf + OFF_W0;
  float* dsts[9] = {w0 + TO_ELA2, w0 + TO_ELM1, w0 + TO_ELM2, w0 + TO_EBL1,
                    w0 + TO_EBL2, w0 + TO_DM1,  w0 + TO_DV1,  w0 + TO_WIH,
                    w0 + TO_WHH};
  const int n4s[9] = {65536, 1048576, 65536, 131072, 65536, 65536, 65536,
                      524288, 524288};
  const int rms[9] = {1023, 1023, 1023, 1023, 1023, 1023, 1023, 8191, 8191};
  const int rss[9] = {10, 10, 10, 10, 10, 10, 10, 13, 13};
  const int Ks[9]  = {256, 4096, 256, 512, 256, 256, 256, 256, 256};
  for (int m = 0; m < 9; ++m) {
    ta.src[m] = srcs[m]; ta.dst[m] = dsts[m]; ta.n4[m] = n4s[m];
    ta.rmask[m] = rms[m]; ta.rshift[m] = rss[m]; ta.K[m] = Ks[m];
  }
  prep_kernel<<<dim3(1024), dim3(256), 0, stream>>>(
      ta, (unsigned*)d_ws, useT ? 9 : 0);

  planner_kernel<<<dim3(NWG), dim3(WGSZ), 0, stream>>>(
      (const float*)d_in[0],  (const float*)d_in[1],  (const float*)d_in[2],
      (const float*)d_in[3],  (const float*)d_in[4],  (const float*)d_in[5],
      (const float*)d_in[6],  (const float*)d_in[7],  (const float*)d_in[8],
      (const float*)d_in[9],  (const float*)d_in[10], (const float*)d_in[11],
      (const float*)d_in[12], (const float*)d_in[13], (const float*)d_in[14],
      wsf, useT, (float*)d_out);
}